// Round 1
// baseline (791.970 us; speedup 1.0000x reference)
//
#include <hip/hip_runtime.h>
#include <stdint.h>

#define HEADS 16
#define NTOK 98
#define HD 32
#define SCALE_Q 0.17677669529663687f

typedef __attribute__((ext_vector_type(4))) float floatx4;
typedef __attribute__((ext_vector_type(8))) short shortx8;

__device__ __forceinline__ unsigned short f2bf(float f) {
  union { float f; unsigned u; } v; v.f = f;
  unsigned r = v.u + 0x7fffu + ((v.u >> 16) & 1u);
  return (unsigned short)(r >> 16);
}

__device__ __forceinline__ void gload_lds16(const void* g, void* l) {
  __builtin_amdgcn_global_load_lds(
      (const __attribute__((address_space(1))) unsigned int*)g,
      (__attribute__((address_space(3))) unsigned int*)l, 16, 0, 0);
}

// ---------------- small prep kernels ----------------
__global__ void convert_w_kernel(const float* __restrict__ qkv_w,
                                 const float* __restrict__ proj_w,
                                 unsigned short* __restrict__ wq,
                                 unsigned short* __restrict__ wp) {
  int idx = blockIdx.x * 256 + threadIdx.x;
  if (idx < 1536 * 512) wq[idx] = f2bf(qkv_w[idx]);
  if (idx < 512 * 512) wp[idx] = f2bf(proj_w[idx]);
}

__global__ void bias_gather_kernel(const float* __restrict__ table,
                                   const int* __restrict__ rel,
                                   float* __restrict__ bias_out) {
  int idx = blockIdx.x * 256 + threadIdx.x;  // 16*9604
  if (idx < HEADS * NTOK * NTOK) {
    int h = idx / (NTOK * NTOK);
    int ij = idx - h * (NTOK * NTOK);
    bias_out[idx] = table[rel[ij] * HEADS + h];
  }
}

// ---------------- QKV GEMM: C[50176,1536] = x[50176,512] @ qkv_w[1536,512]^T ----------------
// 128x128 tile, BK=32, 256 threads (4 waves, each 64x64).
__global__ __launch_bounds__(256, 2)
void qkv_gemm_kernel(const float* __restrict__ x,
                     const unsigned short* __restrict__ wbf,
                     const float* __restrict__ qkv_b,
                     unsigned short* __restrict__ q_out,
                     unsigned short* __restrict__ k_out,
                     unsigned short* __restrict__ v_out) {
  __shared__ unsigned short As[128 * 32];
  __shared__ unsigned short Bs[128 * 32];
  const int tid = threadIdx.x;
  const int wave = tid >> 6, lane = tid & 63;
  const int m0 = blockIdx.x * 128, n0 = blockIdx.y * 128;
  const int wm = wave & 1, wn = wave >> 1;
  const int ln15 = lane & 15, qd = lane >> 4;
  const int bl_r = lane >> 2, bl_s = lane & 3;       // B staging: row/16B-seg
  const int al_r = lane >> 3, al_c = (lane & 7) * 4; // A staging: row/col4

  floatx4 acc[4][4] = {};

  for (int k0 = 0; k0 < 512; k0 += 32) {
    // stage B (bf16 weights) via global_load_lds, 16B/lane
#pragma unroll
    for (int c = 0; c < 2; ++c) {
      int rbase = wave * 32 + c * 16;
      const unsigned short* g =
          wbf + (size_t)(n0 + rbase + bl_r) * 512 + k0 + bl_s * 8;
      gload_lds16((const void*)g, (void*)&Bs[rbase * 32]);
    }
    // stage A: fp32 -> bf16 convert
#pragma unroll
    for (int it = 0; it < 4; ++it) {
      int row = wave * 32 + it * 8 + al_r;
      const float4 f = *(const float4*)(x + (size_t)(m0 + row) * 512 + k0 + al_c);
      ushort4 pk = make_ushort4(f2bf(f.x), f2bf(f.y), f2bf(f.z), f2bf(f.w));
      *(ushort4*)&As[row * 32 + al_c] = pk;
    }
    __syncthreads();

    shortx8 afrag[4], bfrag[4];
#pragma unroll
    for (int mt = 0; mt < 4; ++mt)
      afrag[mt] = *(const shortx8*)&As[(wm * 64 + mt * 16 + ln15) * 32 + qd * 8];
#pragma unroll
    for (int nt = 0; nt < 4; ++nt)
      bfrag[nt] = *(const shortx8*)&Bs[(wn * 64 + nt * 16 + ln15) * 32 + qd * 8];
#pragma unroll
    for (int mt = 0; mt < 4; ++mt)
#pragma unroll
      for (int nt = 0; nt < 4; ++nt)
        acc[mt][nt] = __builtin_amdgcn_mfma_f32_16x16x32_bf16(
            afrag[mt], bfrag[nt], acc[mt][nt], 0, 0, 0);
    __syncthreads();
  }

  // epilogue: + qkv_b, scale q, scatter to [B,H,98,32] bf16
#pragma unroll
  for (int mt = 0; mt < 4; ++mt) {
#pragma unroll
    for (int r = 0; r < 4; ++r) {
      int grow = m0 + wm * 64 + mt * 16 + qd * 4 + r;
      unsigned b = (unsigned)grow / 98u;
      unsigned i = (unsigned)grow - b * 98u;
#pragma unroll
      for (int nt = 0; nt < 4; ++nt) {
        int col = n0 + wn * 64 + nt * 16 + ln15;
        float val = acc[mt][nt][r] + qkv_b[col];
        int which = col >> 9;
        int h = (col >> 5) & 15;
        int d = col & 31;
        size_t oidx = ((size_t)(b * 16 + h) * 98 + i) * 32 + d;
        if (which == 0)      q_out[oidx] = f2bf(val * SCALE_Q);
        else if (which == 1) k_out[oidx] = f2bf(val);
        else                 v_out[oidx] = f2bf(val);
      }
    }
  }
}

// ---------------- attention: one block per (b,h) ----------------
__global__ __launch_bounds__(256, 2)
void attn_kernel(const unsigned short* __restrict__ qg,
                 const unsigned short* __restrict__ kg,
                 const unsigned short* __restrict__ vg,
                 const float* __restrict__ biasg,
                 const float* __restrict__ maskg,
                 unsigned short* __restrict__ outg) {
  __shared__ unsigned short Qs[112 * 40];
  __shared__ unsigned short Ks[112 * 40];
  __shared__ unsigned short Vt[32 * 136];
  __shared__ unsigned short Ps[112 * 136];
  const int tid = threadIdx.x;
  const int bh = blockIdx.x;
  const int b = bh >> 4, h = bh & 15;
  const size_t base = (size_t)bh * (NTOK * HD);
  const int wave = tid >> 6, lane = tid & 63;
  const int ln15 = lane & 15, qd = lane >> 4;

  // phase 0: stage Q/K rows (zero-pad 98..111), zero Vt, zero Ps cols 112..127
  {
    const uint4 z4 = make_uint4(0, 0, 0, 0);
    for (int idx = tid; idx < 112 * 4; idx += 256) {
      int row = idx >> 2, seg = idx & 3;
      uint4 vq = z4, vk = z4;
      if (row < NTOK) {
        vq = *(const uint4*)(qg + base + row * 32 + seg * 8);
        vk = *(const uint4*)(kg + base + row * 32 + seg * 8);
      }
      *(uint4*)&Qs[row * 40 + seg * 8] = vq;
      *(uint4*)&Ks[row * 40 + seg * 8] = vk;
    }
    for (int idx = tid; idx < 544; idx += 256) ((uint4*)Vt)[idx] = z4;
    for (int idx = tid; idx < 224; idx += 256) {
      int row = idx >> 1, seg = idx & 1;
      *(uint4*)&Ps[row * 136 + 112 + seg * 8] = z4;
    }
  }
  __syncthreads();
  // phase 1: transpose V into Vt[d][j]
  for (int idx = tid; idx < NTOK * HD; idx += 256) {
    int j = idx >> 5, d = idx & 31;
    Vt[d * 136 + j] = vg[base + idx];
  }
  __syncthreads();

  // phase 2: S = Q K^T (+bias+mask), softmax, P -> LDS
  float linv[2][4];
  const float* bias_h = biasg + h * (NTOK * NTOK);
  const float* mask_b = maskg + (b & 63) * (NTOK * NTOK);
#pragma unroll
  for (int mslot = 0; mslot < 2; ++mslot) {
    int mt = wave + mslot * 4;
    if (mt >= 7) break;  // wave 3 has only one M-tile
    shortx8 af = *(const shortx8*)&Qs[(mt * 16 + ln15) * 40 + qd * 8];
    float s[7][4];
    {
      floatx4 sacc[7];
#pragma unroll
      for (int nt = 0; nt < 7; ++nt) {
        shortx8 bf = *(const shortx8*)&Ks[(nt * 16 + ln15) * 40 + qd * 8];
        floatx4 z = {};
        sacc[nt] = __builtin_amdgcn_mfma_f32_16x16x32_bf16(af, bf, z, 0, 0, 0);
      }
#pragma unroll
      for (int r = 0; r < 4; ++r) {
        int i = mt * 16 + qd * 4 + r;
#pragma unroll
        for (int nt = 0; nt < 7; ++nt) {
          int j = nt * 16 + ln15;
          float val = -1e30f;
          if (i < NTOK && j < NTOK)
            val = sacc[nt][r] + bias_h[i * NTOK + j] + mask_b[i * NTOK + j];
          s[nt][r] = val;
        }
      }
    }
#pragma unroll
    for (int r = 0; r < 4; ++r) {
      float mx = -1e30f;
#pragma unroll
      for (int nt = 0; nt < 7; ++nt) mx = fmaxf(mx, s[nt][r]);
#pragma unroll
      for (int off = 1; off < 16; off <<= 1)
        mx = fmaxf(mx, __shfl_xor(mx, off, 64));
      float sum = 0.f;
#pragma unroll
      for (int nt = 0; nt < 7; ++nt) {
        float p = (s[nt][r] > -1e29f) ? __expf(s[nt][r] - mx) : 0.f;
        s[nt][r] = p;
        sum += p;
      }
#pragma unroll
      for (int off = 1; off < 16; off <<= 1) sum += __shfl_xor(sum, off, 64);
      linv[mslot][r] = 1.0f / sum;
    }
#pragma unroll
    for (int nt = 0; nt < 7; ++nt)
#pragma unroll
      for (int r = 0; r < 4; ++r) {
        int i = mt * 16 + qd * 4 + r, j = nt * 16 + ln15;
        Ps[i * 136 + j] = f2bf(s[nt][r]);
      }
  }
  __syncthreads();

  // phase 3: O = P @ V, scale rows by 1/l, store bf16 [b, i, h*32+d]
  floatx4 oacc[2][2] = {};
#pragma unroll
  for (int ks = 0; ks < 4; ++ks) {
    shortx8 bv0 = *(const shortx8*)&Vt[(ln15) * 136 + ks * 32 + qd * 8];
    shortx8 bv1 = *(const shortx8*)&Vt[(16 + ln15) * 136 + ks * 32 + qd * 8];
#pragma unroll
    for (int mslot = 0; mslot < 2; ++mslot) {
      int mt = wave + mslot * 4;
      if (mt >= 7) continue;
      shortx8 ap = *(const shortx8*)&Ps[(mt * 16 + ln15) * 136 + ks * 32 + qd * 8];
      oacc[mslot][0] = __builtin_amdgcn_mfma_f32_16x16x32_bf16(ap, bv0, oacc[mslot][0], 0, 0, 0);
      oacc[mslot][1] = __builtin_amdgcn_mfma_f32_16x16x32_bf16(ap, bv1, oacc[mslot][1], 0, 0, 0);
    }
  }
#pragma unroll
  for (int mslot = 0; mslot < 2; ++mslot) {
    int mt = wave + mslot * 4;
    if (mt >= 7) continue;
#pragma unroll
    for (int r = 0; r < 4; ++r) {
      int i = mt * 16 + qd * 4 + r;
      if (i < NTOK) {
        size_t ob = ((size_t)b * NTOK + i) * 512 + h * 32;
#pragma unroll
        for (int nt = 0; nt < 2; ++nt)
          outg[ob + nt * 16 + ln15] = f2bf(oacc[mslot][nt][r] * linv[mslot][r]);
      }
    }
  }
}

// ---------------- proj GEMM: out[50176,512] = attn[50176,512] @ proj_w[512,512]^T + b ----------------
__global__ __launch_bounds__(256, 2)
void proj_gemm_kernel(const unsigned short* __restrict__ a,
                      const unsigned short* __restrict__ wbf,
                      const float* __restrict__ proj_b,
                      float* __restrict__ out) {
  __shared__ unsigned short As[128 * 32];
  __shared__ unsigned short Bs[128 * 32];
  const int tid = threadIdx.x;
  const int wave = tid >> 6, lane = tid & 63;
  const int m0 = blockIdx.x * 128, n0 = blockIdx.y * 128;
  const int wm = wave & 1, wn = wave >> 1;
  const int ln15 = lane & 15, qd = lane >> 4;
  const int bl_r = lane >> 2, bl_s = lane & 3;

  floatx4 acc[4][4] = {};

  for (int k0 = 0; k0 < 512; k0 += 32) {
#pragma unroll
    for (int c = 0; c < 2; ++c) {
      int rbase = wave * 32 + c * 16;
      const unsigned short* ga =
          a + (size_t)(m0 + rbase + bl_r) * 512 + k0 + bl_s * 8;
      gload_lds16((const void*)ga, (void*)&As[rbase * 32]);
      const unsigned short* gb =
          wbf + (size_t)(n0 + rbase + bl_r) * 512 + k0 + bl_s * 8;
      gload_lds16((const void*)gb, (void*)&Bs[rbase * 32]);
    }
    __syncthreads();

    shortx8 afrag[4], bfrag[4];
#pragma unroll
    for (int mt = 0; mt < 4; ++mt)
      afrag[mt] = *(const shortx8*)&As[(wm * 64 + mt * 16 + ln15) * 32 + qd * 8];
#pragma unroll
    for (int nt = 0; nt < 4; ++nt)
      bfrag[nt] = *(const shortx8*)&Bs[(wn * 64 + nt * 16 + ln15) * 32 + qd * 8];
#pragma unroll
    for (int mt = 0; mt < 4; ++mt)
#pragma unroll
      for (int nt = 0; nt < 4; ++nt)
        acc[mt][nt] = __builtin_amdgcn_mfma_f32_16x16x32_bf16(
            afrag[mt], bfrag[nt], acc[mt][nt], 0, 0, 0);
    __syncthreads();
  }

#pragma unroll
  for (int mt = 0; mt < 4; ++mt) {
#pragma unroll
    for (int r = 0; r < 4; ++r) {
      int grow = m0 + wm * 64 + mt * 16 + qd * 4 + r;
#pragma unroll
      for (int nt = 0; nt < 4; ++nt) {
        int col = n0 + wn * 64 + nt * 16 + ln15;
        out[(size_t)grow * 512 + col] = acc[mt][nt][r] + proj_b[col];
      }
    }
  }
}

// ---------------- launch ----------------
extern "C" void kernel_launch(void* const* d_in, const int* in_sizes, int n_in,
                              void* d_out, int out_size, void* d_ws, size_t ws_size,
                              hipStream_t stream) {
  const float* x          = (const float*)d_in[0];
  const float* mask       = (const float*)d_in[1];
  const float* qkv_w      = (const float*)d_in[2];
  const float* qkv_b      = (const float*)d_in[3];
  const float* proj_w     = (const float*)d_in[4];
  const float* proj_b     = (const float*)d_in[5];
  const float* bias_table = (const float*)d_in[6];
  const int*   rel_index  = (const int*)d_in[7];
  float* out = (float*)d_out;

  char* ws = (char*)d_ws;
  unsigned short* ws_qkvw  = (unsigned short*)(ws + 0);          // 1536*512*2 = 1572864
  unsigned short* ws_projw = (unsigned short*)(ws + 1572864);    // 512*512*2  = 524288
  float*          ws_bias  = (float*)(ws + 2097152);             // 16*98*98*4 = 614656
  unsigned short* ws_q     = (unsigned short*)(ws + 2711808);    // 51380224 each
  unsigned short* ws_k     = (unsigned short*)(ws + 54092032);
  unsigned short* ws_v     = (unsigned short*)(ws + 105472256);
  unsigned short* ws_attn  = (unsigned short*)(ws + 156852480);  // end 208232704

  hipLaunchKernelGGL(convert_w_kernel, dim3(3072), dim3(256), 0, stream,
                     qkv_w, proj_w, ws_qkvw, ws_projw);
  hipLaunchKernelGGL(bias_gather_kernel, dim3((HEADS * NTOK * NTOK + 255) / 256),
                     dim3(256), 0, stream, bias_table, rel_index, ws_bias);
  hipLaunchKernelGGL(qkv_gemm_kernel, dim3(392, 12), dim3(256), 0, stream,
                     x, ws_qkvw, qkv_b, ws_q, ws_k, ws_v);
  hipLaunchKernelGGL(attn_kernel, dim3(8192), dim3(256), 0, stream,
                     ws_q, ws_k, ws_v, ws_bias, mask, ws_attn);
  hipLaunchKernelGGL(proj_gemm_kernel, dim3(392, 4), dim3(256), 0, stream,
                     ws_attn, ws_projw, proj_b, out);
}

// Round 2
// 592.573 us; speedup vs baseline: 1.3365x; 1.3365x over previous
//
#include <hip/hip_runtime.h>
#include <stdint.h>

#define HEADS 16
#define NTOK 98
#define HD 32
#define SCALE_Q 0.17677669529663687f

typedef __attribute__((ext_vector_type(4))) float floatx4;
typedef __attribute__((ext_vector_type(8))) short shortx8;

__device__ __forceinline__ unsigned short f2bf(float f) {
  union { float f; unsigned u; } v; v.f = f;
  unsigned r = v.u + 0x7fffu + ((v.u >> 16) & 1u);
  return (unsigned short)(r >> 16);
}
__device__ __forceinline__ float bf2f(unsigned short s) {
  union { unsigned u; float f; } v; v.u = ((unsigned)s) << 16;
  return v.f;
}

__device__ __forceinline__ void gload_lds16(const void* g, void* l) {
  __builtin_amdgcn_global_load_lds(
      (const __attribute__((address_space(1))) unsigned int*)g,
      (__attribute__((address_space(3))) unsigned int*)l, 16, 0, 0);
}

// ---------------- prep kernels ----------------
__global__ void convert_w_kernel(const float* __restrict__ qkv_w,
                                 const float* __restrict__ proj_w,
                                 unsigned short* __restrict__ wq,
                                 unsigned short* __restrict__ wp) {
  int idx = blockIdx.x * 256 + threadIdx.x;
  if (idx < 1536 * 512) wq[idx] = f2bf(qkv_w[idx]);
  if (idx < 512 * 512) wp[idx] = f2bf(proj_w[idx]);
}

// bm[w*16+h][ij] = bias_table[rel[ij]*16+h] + mask[w][ij], bf16
__global__ void bm_kernel(const float* __restrict__ table,
                          const int* __restrict__ rel,
                          const float* __restrict__ mask,
                          unsigned short* __restrict__ bm) {
  int ij = blockIdx.x * 256 + threadIdx.x;
  int wh = blockIdx.y;  // w*16+h
  int w = wh >> 4, h = wh & 15;
  if (ij < NTOK * NTOK) {
    float v = table[rel[ij] * HEADS + h] + mask[w * (NTOK * NTOK) + ij];
    bm[(size_t)wh * (NTOK * NTOK) + ij] = f2bf(v);
  }
}

// ---------------- QKV GEMM: C[50176,1536] = x[50176,512] @ qkv_w[1536,512]^T ----------------
// 128x256 tile, BK=32, 256 threads (4 waves, each 64x128).
__global__ __launch_bounds__(256, 2)
void qkv_gemm_kernel(const float* __restrict__ x,
                     const unsigned short* __restrict__ wbf,
                     const float* __restrict__ qkv_b,
                     unsigned short* __restrict__ q_out,
                     unsigned short* __restrict__ k_out,
                     unsigned short* __restrict__ v_out) {
  __shared__ unsigned short As[128 * 32];
  __shared__ unsigned short Bs[256 * 32];
  const int tid = threadIdx.x;
  const int wave = tid >> 6, lane = tid & 63;
  const int m0 = blockIdx.x * 128, n0 = blockIdx.y * 256;
  const int wm = wave & 1, wn = wave >> 1;
  const int ln15 = lane & 15, qd = lane >> 4;
  const int bl_r = lane >> 2, bl_s = lane & 3;       // B staging: row/16B-seg
  const int al_r = lane >> 3, al_c = (lane & 7) * 4; // A staging: row/col4

  floatx4 acc[4][8] = {};

  for (int k0 = 0; k0 < 512; k0 += 32) {
    // stage B (bf16 weights) via global_load_lds, 16B/lane; 64 rows per wave
#pragma unroll
    for (int c = 0; c < 4; ++c) {
      int rbase = wave * 64 + c * 16;
      const unsigned short* g =
          wbf + (size_t)(n0 + rbase + bl_r) * 512 + k0 + bl_s * 8;
      gload_lds16((const void*)g, (void*)&Bs[rbase * 32]);
    }
    // stage A: fp32 -> bf16 convert, 32 rows per wave
#pragma unroll
    for (int it = 0; it < 4; ++it) {
      int row = wave * 32 + it * 8 + al_r;
      const float4 f = *(const float4*)(x + (size_t)(m0 + row) * 512 + k0 + al_c);
      ushort4 pk = make_ushort4(f2bf(f.x), f2bf(f.y), f2bf(f.z), f2bf(f.w));
      *(ushort4*)&As[row * 32 + al_c] = pk;
    }
    __syncthreads();

    shortx8 afrag[4], bfrag[8];
#pragma unroll
    for (int mt = 0; mt < 4; ++mt)
      afrag[mt] = *(const shortx8*)&As[(wm * 64 + mt * 16 + ln15) * 32 + qd * 8];
#pragma unroll
    for (int nt = 0; nt < 8; ++nt)
      bfrag[nt] = *(const shortx8*)&Bs[(wn * 128 + nt * 16 + ln15) * 32 + qd * 8];
#pragma unroll
    for (int mt = 0; mt < 4; ++mt)
#pragma unroll
      for (int nt = 0; nt < 8; ++nt)
        acc[mt][nt] = __builtin_amdgcn_mfma_f32_16x16x32_bf16(
            afrag[mt], bfrag[nt], acc[mt][nt], 0, 0, 0);
    __syncthreads();
  }

  // epilogue: + qkv_b, scale q, scatter to [B,H,98,32] bf16
#pragma unroll
  for (int mt = 0; mt < 4; ++mt) {
#pragma unroll
    for (int r = 0; r < 4; ++r) {
      int grow = m0 + wm * 64 + mt * 16 + qd * 4 + r;
      unsigned b = (unsigned)grow / 98u;
      unsigned i = (unsigned)grow - b * 98u;
#pragma unroll
      for (int nt = 0; nt < 8; ++nt) {
        int col = n0 + wn * 128 + nt * 16 + ln15;
        float val = acc[mt][nt][r] + qkv_b[col];
        int which = col >> 9;
        int h = (col >> 5) & 15;
        int d = col & 31;
        size_t oidx = ((size_t)(b * 16 + h) * 98 + i) * 32 + d;
        if (which == 0)      q_out[oidx] = f2bf(val * SCALE_Q);
        else if (which == 1) k_out[oidx] = f2bf(val);
        else                 v_out[oidx] = f2bf(val);
      }
    }
  }
}

// ---------------- attention: one block per (b,h) ----------------
__global__ __launch_bounds__(256, 4)
void attn_kernel(const unsigned short* __restrict__ qg,
                 const unsigned short* __restrict__ kg,
                 const unsigned short* __restrict__ vg,
                 const unsigned short* __restrict__ bmg,
                 unsigned short* __restrict__ outg) {
  __shared__ unsigned short Qs[112 * 40];
  __shared__ unsigned short Ks[112 * 40];
  __shared__ unsigned short Vt[32 * 136];
  __shared__ unsigned short Ps[4][16 * 40];  // per-wave private P chunk
  const int tid = threadIdx.x;
  const int bh = blockIdx.x;
  const int b = bh >> 4, h = bh & 15, w = b & 63;
  const size_t base = (size_t)bh * (NTOK * HD);
  const int wave = tid >> 6, lane = tid & 63;
  const int ln15 = lane & 15, qd = lane >> 4;
  const unsigned short* bmh = bmg + (size_t)(w * 16 + h) * (NTOK * NTOK);

  // phase 0: stage Q/K rows (zero-pad 98..111), zero Vt
  {
    const uint4 z4 = make_uint4(0, 0, 0, 0);
    for (int idx = tid; idx < 112 * 4; idx += 256) {
      int row = idx >> 2, seg = idx & 3;
      uint4 vq = z4, vk = z4;
      if (row < NTOK) {
        vq = *(const uint4*)(qg + base + row * 32 + seg * 8);
        vk = *(const uint4*)(kg + base + row * 32 + seg * 8);
      }
      *(uint4*)&Qs[row * 40 + seg * 8] = vq;
      *(uint4*)&Ks[row * 40 + seg * 8] = vk;
    }
    for (int idx = tid; idx < 544; idx += 256) ((uint4*)Vt)[idx] = z4;
  }
  __syncthreads();
  // phase 1: transpose V into Vt[d][j]
  for (int idx = tid; idx < NTOK * HD; idx += 256) {
    int j = idx >> 5, d = idx & 31;
    Vt[d * 136 + j] = vg[base + idx];
  }
  __syncthreads();

  // phase 2+3 per wave: S tile -> softmax -> chunked P@V (no further barriers;
  // Ps[wave] is wave-private: the wave writes and reads only its own 16 rows)
  floatx4 oacc[2];
#pragma unroll
  for (int mslot = 0; mslot < 2; ++mslot) {
    int mt = wave + mslot * 4;
    if (mt >= 7) break;  // wave 3 has one M-tile
    shortx8 af = *(const shortx8*)&Qs[(mt * 16 + ln15) * 40 + qd * 8];
    float s[7][4];
    {
      floatx4 sacc[7];
#pragma unroll
      for (int nt = 0; nt < 7; ++nt) {
        shortx8 bf = *(const shortx8*)&Ks[(nt * 16 + ln15) * 40 + qd * 8];
        floatx4 z = {};
        sacc[nt] = __builtin_amdgcn_mfma_f32_16x16x32_bf16(af, bf, z, 0, 0, 0);
      }
#pragma unroll
      for (int r = 0; r < 4; ++r) {
        int i = mt * 16 + qd * 4 + r;
#pragma unroll
        for (int nt = 0; nt < 7; ++nt) {
          int j = nt * 16 + ln15;
          float val = -1e30f;
          if (i < NTOK && j < NTOK)
            val = sacc[nt][r] + bf2f(bmh[i * NTOK + j]);
          s[nt][r] = val;
        }
      }
    }
    float linv[4];
#pragma unroll
    for (int r = 0; r < 4; ++r) {
      float mx = s[0][r];
#pragma unroll
      for (int nt = 1; nt < 7; ++nt) mx = fmaxf(mx, s[nt][r]);
#pragma unroll
      for (int off = 1; off < 16; off <<= 1)
        mx = fmaxf(mx, __shfl_xor(mx, off, 64));
      float sum = 0.f;
#pragma unroll
      for (int nt = 0; nt < 7; ++nt) {
        float p = __expf(s[nt][r] - mx);
        s[nt][r] = p;
        sum += p;
      }
#pragma unroll
      for (int off = 1; off < 16; off <<= 1) sum += __shfl_xor(sum, off, 64);
      linv[r] = 1.0f / sum;
    }
    // chunked PV: write 16x32 P chunk (wave-private), read A-frag, 2 MFMA
    oacc[0] = (floatx4){};
    oacc[1] = (floatx4){};
#pragma unroll
    for (int ks = 0; ks < 4; ++ks) {
#pragma unroll
      for (int nt2 = 0; nt2 < 2; ++nt2) {
        int nt = ks * 2 + nt2;
#pragma unroll
        for (int r = 0; r < 4; ++r)
          Ps[wave][(qd * 4 + r) * 40 + nt2 * 16 + ln15] = f2bf(s[nt][r]);
      }
      shortx8 ap = *(const shortx8*)&Ps[wave][ln15 * 40 + qd * 8];
      shortx8 bv0 = *(const shortx8*)&Vt[ln15 * 136 + ks * 32 + qd * 8];
      shortx8 bv1 = *(const shortx8*)&Vt[(16 + ln15) * 136 + ks * 32 + qd * 8];
      oacc[0] = __builtin_amdgcn_mfma_f32_16x16x32_bf16(ap, bv0, oacc[0], 0, 0, 0);
      oacc[1] = __builtin_amdgcn_mfma_f32_16x16x32_bf16(ap, bv1, oacc[1], 0, 0, 0);
    }
    // store this M-tile
#pragma unroll
    for (int r = 0; r < 4; ++r) {
      int i = mt * 16 + qd * 4 + r;
      if (i < NTOK) {
        size_t ob = ((size_t)b * NTOK + i) * 512 + h * 32;
#pragma unroll
        for (int vt = 0; vt < 2; ++vt)
          outg[ob + vt * 16 + ln15] = f2bf(oacc[vt][r] * linv[r]);
      }
    }
  }
}

// ---------------- proj GEMM: out[50176,512] = attn[50176,512] @ proj_w[512,512]^T + b ----------------
__global__ __launch_bounds__(256, 2)
void proj_gemm_kernel(const unsigned short* __restrict__ a,
                      const unsigned short* __restrict__ wbf,
                      const float* __restrict__ proj_b,
                      float* __restrict__ out) {
  __shared__ unsigned short As[128 * 32];
  __shared__ unsigned short Bs[128 * 32];
  const int tid = threadIdx.x;
  const int wave = tid >> 6, lane = tid & 63;
  const int m0 = blockIdx.x * 128, n0 = blockIdx.y * 128;
  const int wm = wave & 1, wn = wave >> 1;
  const int ln15 = lane & 15, qd = lane >> 4;
  const int bl_r = lane >> 2, bl_s = lane & 3;

  floatx4 acc[4][4] = {};

  for (int k0 = 0; k0 < 512; k0 += 32) {
#pragma unroll
    for (int c = 0; c < 2; ++c) {
      int rbase = wave * 32 + c * 16;
      const unsigned short* ga =
          a + (size_t)(m0 + rbase + bl_r) * 512 + k0 + bl_s * 8;
      gload_lds16((const void*)ga, (void*)&As[rbase * 32]);
      const unsigned short* gb =
          wbf + (size_t)(n0 + rbase + bl_r) * 512 + k0 + bl_s * 8;
      gload_lds16((const void*)gb, (void*)&Bs[rbase * 32]);
    }
    __syncthreads();

    shortx8 afrag[4], bfrag[4];
#pragma unroll
    for (int mt = 0; mt < 4; ++mt)
      afrag[mt] = *(const shortx8*)&As[(wm * 64 + mt * 16 + ln15) * 32 + qd * 8];
#pragma unroll
    for (int nt = 0; nt < 4; ++nt)
      bfrag[nt] = *(const shortx8*)&Bs[(wn * 64 + nt * 16 + ln15) * 32 + qd * 8];
#pragma unroll
    for (int mt = 0; mt < 4; ++mt)
#pragma unroll
      for (int nt = 0; nt < 4; ++nt)
        acc[mt][nt] = __builtin_amdgcn_mfma_f32_16x16x32_bf16(
            afrag[mt], bfrag[nt], acc[mt][nt], 0, 0, 0);
    __syncthreads();
  }

#pragma unroll
  for (int mt = 0; mt < 4; ++mt) {
#pragma unroll
    for (int r = 0; r < 4; ++r) {
      int grow = m0 + wm * 64 + mt * 16 + qd * 4 + r;
#pragma unroll
      for (int nt = 0; nt < 4; ++nt) {
        int col = n0 + wn * 64 + nt * 16 + ln15;
        out[(size_t)grow * 512 + col] = acc[mt][nt][r] + proj_b[col];
      }
    }
  }
}

// ---------------- launch ----------------
extern "C" void kernel_launch(void* const* d_in, const int* in_sizes, int n_in,
                              void* d_out, int out_size, void* d_ws, size_t ws_size,
                              hipStream_t stream) {
  const float* x          = (const float*)d_in[0];
  const float* mask       = (const float*)d_in[1];
  const float* qkv_w      = (const float*)d_in[2];
  const float* qkv_b      = (const float*)d_in[3];
  const float* proj_w     = (const float*)d_in[4];
  const float* proj_b     = (const float*)d_in[5];
  const float* bias_table = (const float*)d_in[6];
  const int*   rel_index  = (const int*)d_in[7];
  float* out = (float*)d_out;

  char* ws = (char*)d_ws;
  unsigned short* ws_qkvw  = (unsigned short*)(ws + 0);           // 1,572,864
  unsigned short* ws_projw = (unsigned short*)(ws + 1572864);     //   524,288
  unsigned short* ws_bm    = (unsigned short*)(ws + 2097152);     // 19,668,992
  unsigned short* ws_q     = (unsigned short*)(ws + 21766144);    // 51,380,224
  unsigned short* ws_k     = (unsigned short*)(ws + 73146368);
  unsigned short* ws_v     = (unsigned short*)(ws + 124526592);
  unsigned short* ws_attn  = (unsigned short*)(ws + 175906816);   // end 227,287,040

  hipLaunchKernelGGL(convert_w_kernel, dim3(3072), dim3(256), 0, stream,
                     qkv_w, proj_w, ws_qkvw, ws_projw);
  hipLaunchKernelGGL(bm_kernel, dim3(38, 1024), dim3(256), 0, stream,
                     bias_table, rel_index, mask, ws_bm);
  hipLaunchKernelGGL(qkv_gemm_kernel, dim3(392, 6), dim3(256), 0, stream,
                     x, ws_qkvw, qkv_b, ws_q, ws_k, ws_v);
  hipLaunchKernelGGL(attn_kernel, dim3(8192), dim3(256), 0, stream,
                     ws_q, ws_k, ws_v, ws_bm, ws_attn);
  hipLaunchKernelGGL(proj_gemm_kernel, dim3(392, 4), dim3(256), 0, stream,
                     ws_attn, ws_projw, proj_b, out);
}

// Round 3
// 525.335 us; speedup vs baseline: 1.5076x; 1.1280x over previous
//
#include <hip/hip_runtime.h>
#include <stdint.h>

#define HEADS 16
#define NTOK 98
#define HD 32
#define SCALE_Q 0.17677669529663687f

typedef __attribute__((ext_vector_type(4))) float floatx4;
typedef __attribute__((ext_vector_type(8))) short shortx8;

__device__ __forceinline__ unsigned short f2bf(float f) {
  union { float f; unsigned u; } v; v.f = f;
  unsigned r = v.u + 0x7fffu + ((v.u >> 16) & 1u);
  return (unsigned short)(r >> 16);
}
__device__ __forceinline__ float bf2f(unsigned short s) {
  union { unsigned u; float f; } v; v.u = ((unsigned)s) << 16;
  return v.f;
}

__device__ __forceinline__ void gload_lds16(const void* g, void* l) {
  __builtin_amdgcn_global_load_lds(
      (const __attribute__((address_space(1))) unsigned int*)g,
      (__attribute__((address_space(3))) unsigned int*)l, 16, 0, 0);
}

// ---------------- prep kernels ----------------
__global__ void convert_x_kernel(const float* __restrict__ x,
                                 unsigned short* __restrict__ xbf) {
  int idx = blockIdx.x * 256 + threadIdx.x;  // one per 8 elems; 3,211,264 total
  const float4 f0 = *(const float4*)(x + (size_t)idx * 8);
  const float4 f1 = *(const float4*)(x + (size_t)idx * 8 + 4);
  union { ushort us[8]; uint4 u4; } pk;
  pk.us[0] = f2bf(f0.x); pk.us[1] = f2bf(f0.y);
  pk.us[2] = f2bf(f0.z); pk.us[3] = f2bf(f0.w);
  pk.us[4] = f2bf(f1.x); pk.us[5] = f2bf(f1.y);
  pk.us[6] = f2bf(f1.z); pk.us[7] = f2bf(f1.w);
  *(uint4*)(xbf + (size_t)idx * 8) = pk.u4;
}

__global__ void convert_w_kernel(const float* __restrict__ qkv_w,
                                 const float* __restrict__ proj_w,
                                 unsigned short* __restrict__ wq,
                                 unsigned short* __restrict__ wp) {
  int idx = blockIdx.x * 256 + threadIdx.x;
  if (idx < 1536 * 512) wq[idx] = f2bf(qkv_w[idx]);
  if (idx < 512 * 512) wp[idx] = f2bf(proj_w[idx]);
}

// bm[w*16+h][ij] = bias_table[rel[ij]*16+h] + mask[w][ij], bf16
__global__ void bm_kernel(const float* __restrict__ table,
                          const int* __restrict__ rel,
                          const float* __restrict__ mask,
                          unsigned short* __restrict__ bm) {
  int ij = blockIdx.x * 256 + threadIdx.x;
  int wh = blockIdx.y;  // w*16+h
  int w = wh >> 4, h = wh & 15;
  if (ij < NTOK * NTOK) {
    float v = table[rel[ij] * HEADS + h] + mask[w * (NTOK * NTOK) + ij];
    bm[(size_t)wh * (NTOK * NTOK) + ij] = f2bf(v);
  }
}

// ---------------- QKV GEMM: C[50176,1536] = xbf[50176,512] @ qkv_w[1536,512]^T ----------------
// 128x256 tile, BK=32, 256 threads (4 waves, each 64x128), both operands via global_load_lds.
__global__ __launch_bounds__(256, 2)
void qkv_gemm_kernel(const unsigned short* __restrict__ xbf,
                     const unsigned short* __restrict__ wbf,
                     const float* __restrict__ qkv_b,
                     unsigned short* __restrict__ q_out,
                     unsigned short* __restrict__ k_out,
                     unsigned short* __restrict__ v_out) {
  __shared__ unsigned short As[128 * 32];
  __shared__ unsigned short Bs[256 * 32];
  const int tid = threadIdx.x;
  const int wave = tid >> 6, lane = tid & 63;
  const int m0 = blockIdx.x * 128, n0 = blockIdx.y * 256;
  const int wm = wave & 1, wn = wave >> 1;
  const int ln15 = lane & 15, qd = lane >> 4;
  const int bl_r = lane >> 2, bl_s = lane & 3;  // staging: row / 16B-seg

  floatx4 acc[4][8] = {};

  for (int k0 = 0; k0 < 512; k0 += 32) {
#pragma unroll
    for (int c = 0; c < 2; ++c) {
      int rbase = wave * 32 + c * 16;
      const unsigned short* g =
          xbf + (size_t)(m0 + rbase + bl_r) * 512 + k0 + bl_s * 8;
      gload_lds16((const void*)g, (void*)&As[rbase * 32]);
    }
#pragma unroll
    for (int c = 0; c < 4; ++c) {
      int rbase = wave * 64 + c * 16;
      const unsigned short* g =
          wbf + (size_t)(n0 + rbase + bl_r) * 512 + k0 + bl_s * 8;
      gload_lds16((const void*)g, (void*)&Bs[rbase * 32]);
    }
    __syncthreads();

    shortx8 afrag[4], bfrag[8];
#pragma unroll
    for (int mt = 0; mt < 4; ++mt)
      afrag[mt] = *(const shortx8*)&As[(wm * 64 + mt * 16 + ln15) * 32 + qd * 8];
#pragma unroll
    for (int nt = 0; nt < 8; ++nt)
      bfrag[nt] = *(const shortx8*)&Bs[(wn * 128 + nt * 16 + ln15) * 32 + qd * 8];
#pragma unroll
    for (int mt = 0; mt < 4; ++mt)
#pragma unroll
      for (int nt = 0; nt < 8; ++nt)
        acc[mt][nt] = __builtin_amdgcn_mfma_f32_16x16x32_bf16(
            afrag[mt], bfrag[nt], acc[mt][nt], 0, 0, 0);
    __syncthreads();
  }

  // epilogue: + qkv_b, scale q, scatter to [B,H,98,32] bf16
#pragma unroll
  for (int mt = 0; mt < 4; ++mt) {
#pragma unroll
    for (int r = 0; r < 4; ++r) {
      int grow = m0 + wm * 64 + mt * 16 + qd * 4 + r;
      unsigned b = (unsigned)grow / 98u;
      unsigned i = (unsigned)grow - b * 98u;
#pragma unroll
      for (int nt = 0; nt < 8; ++nt) {
        int col = n0 + wn * 128 + nt * 16 + ln15;
        float val = acc[mt][nt][r] + qkv_b[col];
        int which = col >> 9;
        int h = (col >> 5) & 15;
        int d = col & 31;
        size_t oidx = ((size_t)(b * 16 + h) * 98 + i) * 32 + d;
        if (which == 0)      q_out[oidx] = f2bf(val * SCALE_Q);
        else if (which == 1) k_out[oidx] = f2bf(val);
        else                 v_out[oidx] = f2bf(val);
      }
    }
  }
}

// ---------------- attention: one block per (b,h), Q/K frags direct from global ----------------
__global__ __launch_bounds__(256, 6)
void attn_kernel(const unsigned short* __restrict__ qg,
                 const unsigned short* __restrict__ kg,
                 const unsigned short* __restrict__ vg,
                 const unsigned short* __restrict__ bmg,
                 unsigned short* __restrict__ outg) {
  __shared__ unsigned short Vt[32 * 136];
  __shared__ unsigned short Ps[4][16 * 40];  // per-wave private P chunk
  const int tid = threadIdx.x;
  const int bh = blockIdx.x;
  const int b = bh >> 4, h = bh & 15, w = b & 63;
  const size_t base = (size_t)bh * (NTOK * HD);
  const int wave = tid >> 6, lane = tid & 63;
  const int ln15 = lane & 15, qd = lane >> 4;
  const unsigned short* bmh = bmg + (size_t)(w * 16 + h) * (NTOK * NTOK);

  // zero Vt (pad cols 98..135 must be finite-zero for the PV MFMA)
  for (int idx = tid; idx < 544; idx += 256)
    ((uint4*)Vt)[idx] = make_uint4(0, 0, 0, 0);
  __syncthreads();
  // transpose V into Vt[d][j]: 16B loads, 8 scalar LDS writes each
  for (int t = tid; t < 392; t += 256) {
    int i = t >> 2, seg = t & 3;
    union { uint4 u4; unsigned short us[8]; } u;
    u.u4 = *(const uint4*)(vg + base + i * 32 + seg * 8);
    int d0 = seg * 8;
#pragma unroll
    for (int e = 0; e < 8; ++e) Vt[(d0 + e) * 136 + i] = u.us[e];
  }
  __syncthreads();

  // per wave: S tile -> softmax -> chunked P@V (Ps[wave] is wave-private)
  floatx4 oacc[2];
#pragma unroll
  for (int mslot = 0; mslot < 2; ++mslot) {
    int mt = wave + mslot * 4;
    if (mt >= 7) break;  // wave 3 has one M-tile
    shortx8 af = *(const shortx8*)(qg + base + (mt * 16 + ln15) * 32 + qd * 8);
    float s[7][4];
    {
      floatx4 sacc[7];
#pragma unroll
      for (int nt = 0; nt < 7; ++nt) {
        shortx8 bf = *(const shortx8*)(kg + base + (nt * 16 + ln15) * 32 + qd * 8);
        floatx4 z = {};
        sacc[nt] = __builtin_amdgcn_mfma_f32_16x16x32_bf16(af, bf, z, 0, 0, 0);
      }
#pragma unroll
      for (int r = 0; r < 4; ++r) {
        int i = mt * 16 + qd * 4 + r;
        int ii = i < 97 ? i : 97;
#pragma unroll
        for (int nt = 0; nt < 7; ++nt) {
          int j = nt * 16 + ln15;
          int jj = j < 97 ? j : 97;
          float bmv = bf2f(bmh[ii * NTOK + jj]);  // unconditional -> batch issue
          s[nt][r] = (i < NTOK && j < NTOK) ? sacc[nt][r] + bmv : -1e30f;
        }
      }
    }
    float linv[4];
#pragma unroll
    for (int r = 0; r < 4; ++r) {
      float mx = s[0][r];
#pragma unroll
      for (int nt = 1; nt < 7; ++nt) mx = fmaxf(mx, s[nt][r]);
#pragma unroll
      for (int off = 1; off < 16; off <<= 1)
        mx = fmaxf(mx, __shfl_xor(mx, off, 64));
      float sum = 0.f;
#pragma unroll
      for (int nt = 0; nt < 7; ++nt) {
        float p = __expf(s[nt][r] - mx);
        s[nt][r] = p;
        sum += p;
      }
#pragma unroll
      for (int off = 1; off < 16; off <<= 1) sum += __shfl_xor(sum, off, 64);
      linv[r] = 1.0f / sum;
    }
    // chunked PV: write 16x32 P chunk (wave-private), read A-frag, 2 MFMA
    oacc[0] = (floatx4){};
    oacc[1] = (floatx4){};
#pragma unroll
    for (int ks = 0; ks < 4; ++ks) {
#pragma unroll
      for (int nt2 = 0; nt2 < 2; ++nt2) {
        int nt = ks * 2 + nt2;
#pragma unroll
        for (int r = 0; r < 4; ++r)
          Ps[wave][(qd * 4 + r) * 40 + nt2 * 16 + ln15] = f2bf(s[nt][r]);
      }
      shortx8 ap = *(const shortx8*)&Ps[wave][ln15 * 40 + qd * 8];
      shortx8 bv0 = *(const shortx8*)&Vt[ln15 * 136 + ks * 32 + qd * 8];
      shortx8 bv1 = *(const shortx8*)&Vt[(16 + ln15) * 136 + ks * 32 + qd * 8];
      oacc[0] = __builtin_amdgcn_mfma_f32_16x16x32_bf16(ap, bv0, oacc[0], 0, 0, 0);
      oacc[1] = __builtin_amdgcn_mfma_f32_16x16x32_bf16(ap, bv1, oacc[1], 0, 0, 0);
    }
    // store this M-tile to [b*98+i][512] at col h*32
#pragma unroll
    for (int r = 0; r < 4; ++r) {
      int i = mt * 16 + qd * 4 + r;
      if (i < NTOK) {
        size_t ob = ((size_t)b * NTOK + i) * 512 + h * 32;
#pragma unroll
        for (int vt = 0; vt < 2; ++vt)
          outg[ob + vt * 16 + ln15] = f2bf(oacc[vt][r] * linv[r]);
      }
    }
  }
}

// ---------------- proj GEMM: out[50176,512] = attn[50176,512] @ proj_w[512,512]^T + b ----------------
__global__ __launch_bounds__(256, 2)
void proj_gemm_kernel(const unsigned short* __restrict__ a,
                      const unsigned short* __restrict__ wbf,
                      const float* __restrict__ proj_b,
                      float* __restrict__ out) {
  __shared__ unsigned short As[128 * 32];
  __shared__ unsigned short Bs[128 * 32];
  const int tid = threadIdx.x;
  const int wave = tid >> 6, lane = tid & 63;
  const int m0 = blockIdx.x * 128, n0 = blockIdx.y * 128;
  const int wm = wave & 1, wn = wave >> 1;
  const int ln15 = lane & 15, qd = lane >> 4;
  const int bl_r = lane >> 2, bl_s = lane & 3;

  floatx4 acc[4][4] = {};

  for (int k0 = 0; k0 < 512; k0 += 32) {
#pragma unroll
    for (int c = 0; c < 2; ++c) {
      int rbase = wave * 32 + c * 16;
      const unsigned short* ga =
          a + (size_t)(m0 + rbase + bl_r) * 512 + k0 + bl_s * 8;
      gload_lds16((const void*)ga, (void*)&As[rbase * 32]);
      const unsigned short* gb =
          wbf + (size_t)(n0 + rbase + bl_r) * 512 + k0 + bl_s * 8;
      gload_lds16((const void*)gb, (void*)&Bs[rbase * 32]);
    }
    __syncthreads();

    shortx8 afrag[4], bfrag[4];
#pragma unroll
    for (int mt = 0; mt < 4; ++mt)
      afrag[mt] = *(const shortx8*)&As[(wm * 64 + mt * 16 + ln15) * 32 + qd * 8];
#pragma unroll
    for (int nt = 0; nt < 4; ++nt)
      bfrag[nt] = *(const shortx8*)&Bs[(wn * 64 + nt * 16 + ln15) * 32 + qd * 8];
#pragma unroll
    for (int mt = 0; mt < 4; ++mt)
#pragma unroll
      for (int nt = 0; nt < 4; ++nt)
        acc[mt][nt] = __builtin_amdgcn_mfma_f32_16x16x32_bf16(
            afrag[mt], bfrag[nt], acc[mt][nt], 0, 0, 0);
    __syncthreads();
  }

#pragma unroll
  for (int mt = 0; mt < 4; ++mt) {
#pragma unroll
    for (int r = 0; r < 4; ++r) {
      int grow = m0 + wm * 64 + mt * 16 + qd * 4 + r;
#pragma unroll
      for (int nt = 0; nt < 4; ++nt) {
        int col = n0 + wn * 64 + nt * 16 + ln15;
        out[(size_t)grow * 512 + col] = acc[mt][nt][r] + proj_b[col];
      }
    }
  }
}

// ---------------- launch ----------------
extern "C" void kernel_launch(void* const* d_in, const int* in_sizes, int n_in,
                              void* d_out, int out_size, void* d_ws, size_t ws_size,
                              hipStream_t stream) {
  const float* x          = (const float*)d_in[0];
  const float* mask       = (const float*)d_in[1];
  const float* qkv_w      = (const float*)d_in[2];
  const float* qkv_b      = (const float*)d_in[3];
  const float* proj_w     = (const float*)d_in[4];
  const float* proj_b     = (const float*)d_in[5];
  const float* bias_table = (const float*)d_in[6];
  const int*   rel_index  = (const int*)d_in[7];
  float* out = (float*)d_out;

  char* ws = (char*)d_ws;
  unsigned short* ws_qkvw  = (unsigned short*)(ws + 0);           // 1,572,864
  unsigned short* ws_projw = (unsigned short*)(ws + 1572864);     //   524,288
  unsigned short* ws_bm    = (unsigned short*)(ws + 2097152);     // 19,668,992
  unsigned short* ws_q     = (unsigned short*)(ws + 21766144);    // 51,380,224
  unsigned short* ws_k     = (unsigned short*)(ws + 73146368);
  unsigned short* ws_v     = (unsigned short*)(ws + 124526592);
  unsigned short* ws_attn  = (unsigned short*)(ws + 175906816);   // end 227,287,040
  unsigned short* ws_xbf   = ws_attn;  // aliased: xbf dead before attn writes

  hipLaunchKernelGGL(convert_x_kernel, dim3(12544), dim3(256), 0, stream,
                     x, ws_xbf);
  hipLaunchKernelGGL(convert_w_kernel, dim3(3072), dim3(256), 0, stream,
                     qkv_w, proj_w, ws_qkvw, ws_projw);
  hipLaunchKernelGGL(bm_kernel, dim3(38, 1024), dim3(256), 0, stream,
                     bias_table, rel_index, mask, ws_bm);
  hipLaunchKernelGGL(qkv_gemm_kernel, dim3(392, 6), dim3(256), 0, stream,
                     ws_xbf, ws_qkvw, qkv_b, ws_q, ws_k, ws_v);
  hipLaunchKernelGGL(attn_kernel, dim3(8192), dim3(256), 0, stream,
                     ws_q, ws_k, ws_v, ws_bm, ws_attn);
  hipLaunchKernelGGL(proj_gemm_kernel, dim3(392, 4), dim3(256), 0, stream,
                     ws_attn, ws_projw, proj_b, out);
}